// Round 7
// baseline (238.442 us; speedup 1.0000x reference)
//
#include <hip/hip_runtime.h>

#define B_    8
#define N_    8192
#define M_    1024
#define C1_   256
#define C2_   512
#define CIN_  768
#define CMID_ 256
#define COUT_ 256

typedef __attribute__((ext_vector_type(8))) __bf16 bf16x8;           // 4 VGPRs, MFMA A/B frag
typedef __attribute__((ext_vector_type(4))) float f32x4;             // MFMA C/D frag
typedef __attribute__((ext_vector_type(4))) unsigned short u16x4;
typedef __attribute__((ext_vector_type(8))) unsigned short u16x8;

__device__ __forceinline__ unsigned short f2bf(float f) {
  union { float f; unsigned u; } v; v.f = f;
  unsigned r = v.u + 0x7FFFu + ((v.u >> 16) & 1u);   // RNE
  return (unsigned short)(r >> 16);
}
__device__ __forceinline__ float bf2f(unsigned short h) {
  union { unsigned u; float f; } v; v.u = ((unsigned)h) << 16; return v.f;
}

// async global -> LDS, 16B per lane per wave-instruction (dest = uniform base + lane*16)
__device__ __forceinline__ void gload16(const void* g, void* l) {
  __builtin_amdgcn_global_load_lds((const __attribute__((address_space(1))) unsigned int*)g,
                                   (__attribute__((address_space(3))) unsigned int*)l, 16, 0, 0);
}

// ---------------- small utility kernels ----------------

__global__ void k_cast(const float* __restrict__ in, unsigned short* __restrict__ out, int n) {
  int i = blockIdx.x * 256 + threadIdx.x;
  if (i < n) out[i] = f2bf(in[i]);
}

// known_feats (B, C2, M) f32 -> kft (B, M, C2) f32
__global__ void k_tr_kf(const float* __restrict__ in, float* __restrict__ out) {
  __shared__ float t[32][33];
  int b = blockIdx.z;
  int c0 = blockIdx.x * 32, m0 = blockIdx.y * 32;
  int tx = threadIdx.x, ty = threadIdx.y;
  const float* ip = in + ((size_t)b * C2_ + c0) * M_ + m0;
#pragma unroll
  for (int i = 0; i < 32; i += 8) t[ty + i][tx] = ip[(size_t)(ty + i) * M_ + tx];
  __syncthreads();
  float* op = out + ((size_t)b * M_ + m0) * C2_ + c0;
#pragma unroll
  for (int i = 0; i < 32; i += 8) op[(size_t)(ty + i) * C2_ + tx] = t[tx][ty + i];
}

// unknow_feats (B, C1, N) f32 -> xt[b][n][0:256] bf16 (row stride CIN_)
__global__ void k_tr_uf(const float* __restrict__ in, unsigned short* __restrict__ out) {
  __shared__ float t[32][33];
  int b = blockIdx.z;
  int c0 = blockIdx.x * 32, n0 = blockIdx.y * 32;
  int tx = threadIdx.x, ty = threadIdx.y;
  const float* ip = in + ((size_t)b * C1_ + c0) * N_ + n0;
#pragma unroll
  for (int i = 0; i < 32; i += 8) t[ty + i][tx] = ip[(size_t)(ty + i) * N_ + tx];
  __syncthreads();
  unsigned short* op = out + ((size_t)b * N_ + n0) * CIN_ + c0;
#pragma unroll
  for (int i = 0; i < 32; i += 8) op[(size_t)(ty + i) * CIN_ + tx] = f2bf(t[tx][ty + i]);
}

// ---------------- three_nn: exact fp32 (d, idx)-lex semantics, 8 lanes/query ----------------

__device__ __forceinline__ void ins3(float db, int ib, float& d0, int& i0,
                                     float& d1, int& i1, float& d2, int& i2) {
  if (db < d2 || (db == d2 && ib < i2)) {
    if (db < d1 || (db == d1 && ib < i1)) {
      d2 = d1; i2 = i1;
      if (db < d0 || (db == d0 && ib < i0)) { d1 = d0; i1 = i0; d0 = db; i0 = ib; }
      else                                  { d1 = db; i1 = ib; }
    } else { d2 = db; i2 = ib; }
  }
}

__global__ __launch_bounds__(256) void k_three_nn(const float* __restrict__ unknown,
                                                  const float* __restrict__ known,
                                                  int* __restrict__ idx, float* __restrict__ wgt) {
  __shared__ __align__(16) float kpts[M_][4];
  int b = blockIdx.x >> 8;
  int n0 = (blockIdx.x & 255) << 5;
  for (int i = threadIdx.x; i < M_; i += 256) {
    const float* kp = known + ((size_t)b * M_ + i) * 3;
    kpts[i][0] = kp[0]; kpts[i][1] = kp[1]; kpts[i][2] = kp[2];
  }
  __syncthreads();
  const int l = threadIdx.x & 63;
  const int j = l & 7;
  const int q = ((threadIdx.x >> 6) << 3) + (l >> 3);
  const int n = n0 + q;
  const float* up = unknown + ((size_t)b * N_ + n) * 3;
  float ux = up[0], uy = up[1], uz = up[2];
  float d0 = 1e30f, d1 = 1e30f, d2v = 1e30f;
  int i0 = 0, i1 = 0, i2 = 0;
  for (int t = 0; t < 128; ++t) {
    int i = t * 8 + j;
    f32x4 p = *(const f32x4*)kpts[i];
    float dx = __fsub_rn(ux, p[0]);
    float dy = __fsub_rn(uy, p[1]);
    float dz = __fsub_rn(uz, p[2]);
    float d = __fadd_rn(__fadd_rn(__fmul_rn(dx, dx), __fmul_rn(dy, dy)), __fmul_rn(dz, dz));
    if (d < d2v) {
      if (d < d1) {
        if (d < d0) { d2v = d1; i2 = i1; d1 = d0; i1 = i0; d0 = d; i0 = i; }
        else        { d2v = d1; i2 = i1; d1 = d;  i1 = i; }
      } else        { d2v = d;  i2 = i; }
    }
  }
#pragma unroll
  for (int m = 1; m <= 4; m <<= 1) {
    float e0 = __shfl_xor(d0, m), e1 = __shfl_xor(d1, m), e2 = __shfl_xor(d2v, m);
    int   f0 = __shfl_xor(i0, m), f1 = __shfl_xor(i1, m), f2 = __shfl_xor(i2, m);
    ins3(e0, f0, d0, i0, d1, i1, d2v, i2);
    ins3(e1, f1, d0, i0, d1, i1, d2v, i2);
    ins3(e2, f2, d0, i0, d1, i1, d2v, i2);
  }
  if (j == 0) {
    float w0 = 1.f / (d0 + 1e-8f), w1 = 1.f / (d1 + 1e-8f), w2 = 1.f / (d2v + 1e-8f);
    float s = w0 + w1 + w2;
    size_t base = ((size_t)b * N_ + n) * 3;
    idx[base] = i0; idx[base + 1] = i1; idx[base + 2] = i2;
    wgt[base] = w0 / s; wgt[base + 1] = w1 / s; wgt[base + 2] = w2 / s;
  }
}

// interp -> xt[b][n][256:768] bf16; 8 points/block, 32 lanes each, float4 gathers
__global__ __launch_bounds__(256) void k_interp(const float* __restrict__ kft, const int* __restrict__ idx,
                                                const float* __restrict__ wgt, unsigned short* __restrict__ xt) {
  int pb = blockIdx.x * 8 + (threadIdx.x >> 5);
  int lane = threadIdx.x & 31;
  int b = pb >> 13;
  size_t t3 = (size_t)pb * 3;
  int i0 = idx[t3], i1 = idx[t3 + 1], i2 = idx[t3 + 2];
  float w0 = wgt[t3], w1 = wgt[t3 + 1], w2 = wgt[t3 + 2];
  const f32x4* f0 = (const f32x4*)(kft + ((size_t)b * M_ + i0) * C2_);
  const f32x4* f1 = (const f32x4*)(kft + ((size_t)b * M_ + i1) * C2_);
  const f32x4* f2 = (const f32x4*)(kft + ((size_t)b * M_ + i2) * C2_);
  unsigned short* o = xt + (size_t)pb * CIN_ + C1_;
#pragma unroll
  for (int k = 0; k < 4; ++k) {
    int c4 = lane + 32 * k;
    f32x4 a = f0[c4], bb = f1[c4], cc = f2[c4];
    u16x4 r;
#pragma unroll
    for (int e = 0; e < 4; ++e) r[e] = f2bf(w0 * a[e] + w1 * bb[e] + w2 * cc[e]);
    *(u16x4*)(o + 4 * c4) = r;
  }
}

// ---------------- bf16 MFMA GEMM: 256-wide M (full channel dim), counted-vmcnt pipeline ----
// C(256 x 8192) = A(256 x K) * X^T, X point-major (N x K). Grid 32 n-tiles x 8 batches = 256
// blocks = 1/CU. 512 threads = 8 waves (2M x 4N), wave tile 128(o) x 64(n) = 8x4 f32x4 acc.
// B-operand: global -> VGPR frags directly (each lane's frag = one contiguous 16-B read of X^T;
//   same lane->(n,k) map as the R2-R6 LDS path, which refchecks). No B LDS at all.
// A-operand: global_load_lds double-buffer (2 x 32 KB), XOR-involution swizzle (R5: 0 conflicts).
// Pipeline per K-step t: [vmcnt(8) -> s_barrier -> sched_barrier]  (A(t) guaranteed in LDS;
//   A(t+1)/B(t+1) stay IN FLIGHT across the barrier — the counted-vmcnt lever, T4)
//   then issue A(t+1)->buf^1, B(t+1)->regs; then 16 ds_read + 64 MFMA (setprio).
// Race-freedom: writes to buf[(t+1)&1] are ordered before reads by the NEXT gate+barrier;
//   same-parity restaging (t+2) is separated from t's readers by the intervening barrier.
// sched_barrier(0) fences pin [A-issues][B-issues] queue order so vmcnt(8) counts exactly B(t+1).
// BN=true (gemm2): BN1+ReLU applied on B regs; scale/shift distributed via __shfl (no vmem).
// Epilogue: per-block partial BN stats to unique slots (no atomics), point-major u16x4 C stores.

template <int K, bool BN>
__global__ __launch_bounds__(512, 2) void gemm256(const unsigned short* __restrict__ A,
                                                  const unsigned short* __restrict__ Bm,
                                                  unsigned short* __restrict__ C,
                                                  float* __restrict__ psum, float* __restrict__ psq,
                                                  const float* __restrict__ scale,
                                                  const float* __restrict__ shift) {
  constexpr int NK = K / 64;
  __shared__ __align__(16) char lds[65536];     // A dbuf: 2 x (256 rows x 128 B)
  const int tid = threadIdx.x;
  const int l = tid & 63;
  const int wv = tid >> 6;          // 0..7
  const int wr = wv >> 2;           // o half (0..1)
  const int wc = wv & 3;            // n quarter (0..3)
  const int b = blockIdx.y;
  const int n0 = blockIdx.x * 256;
  const char* Abase = (const char*)A;
  const char* Bbase = (const char*)Bm + ((size_t)b * N_ + n0) * (size_t)(K * 2);

  f32x4 acc[8][4];
#pragma unroll
  for (int i = 0; i < 8; ++i)
#pragma unroll
    for (int j = 0; j < 4; ++j) acc[i][j] = f32x4{0.f, 0.f, 0.f, 0.f};

  // BN scale/shift held register-distributed: lane l owns channel kt*64 + l for each kt
  float scR[NK], shR[NK];
  if (BN) {
#pragma unroll
    for (int t = 0; t < NK; ++t) { scR[t] = scale[t * 64 + l]; shR[t] = shift[t * 64 + l]; }
  }

  // A staging: wave wv stages rows wv*32..wv*32+31 (4 x gload16). Linear LDS dest;
  // global col granule pre-swizzled by the involution g ^= (row&7)  (row&7 == l>>3).
  const int adst = wv * 4096;
  const size_t arow = (size_t)(wv * 32 + (l >> 3));
  const int gcol = ((l & 7) ^ (l >> 3)) * 16;
  // B frag base: lane l covers n-row wc*64 + ni*16 + (l&15), k-granule (l>>4)
  const char* Brow = Bbase + (size_t)(wc * 64 + (l & 15)) * (K * 2) + (l >> 4) * 16;

  auto issueA = [&](int kt, int buf) {
#pragma unroll
    for (int i = 0; i < 4; ++i)
      gload16(Abase + (arow + i * 8) * (size_t)(K * 2) + kt * 128 + gcol,
              lds + buf * 32768 + adst + i * 1024);
  };
  auto loadB = [&](bf16x8* bf, int kt) {
#pragma unroll
    for (int ni = 0; ni < 4; ++ni)
#pragma unroll
      for (int kk = 0; kk < 2; ++kk)
        bf[ni * 2 + kk] = *(const bf16x8*)(Brow + (size_t)(ni * 16) * (K * 2) + kt * 128 + kk * 64);
  };
  auto compute = [&](int buf, bf16x8* bf, int kt) {
    if (BN) {   // BN1+ReLU on B regs; scale[kt*64 + (kk*32 + g*8 + e)] via shfl from lane owner
#pragma unroll
      for (int f = 0; f < 8; ++f) {
        int kk = f & 1;
        u16x8 v = *(u16x8*)&bf[f];
        u16x8 r;
#pragma unroll
        for (int e = 0; e < 8; ++e) {
          int src = kk * 32 + (l >> 4) * 8 + e;
          float sc = __shfl(scR[kt], src), sh = __shfl(shR[kt], src);
          r[e] = f2bf(fmaxf(bf2f(v[e]) * sc + sh, 0.f));
        }
        bf[f] = *(bf16x8*)&r;
      }
    }
    const char* base = lds + buf * 32768;
    __builtin_amdgcn_s_setprio(1);
#pragma unroll
    for (int kk = 0; kk < 2; ++kk) {
      bf16x8 af[8];
#pragma unroll
      for (int mi = 0; mi < 8; ++mi) {
        int row = wr * 128 + mi * 16 + (l & 15);
        int g = (kk * 4 + (l >> 4)) ^ (row & 7);
        af[mi] = *(const bf16x8*)(base + row * 128 + g * 16);
      }
#pragma unroll
      for (int mi = 0; mi < 8; ++mi)
#pragma unroll
        for (int ni = 0; ni < 4; ++ni)
          acc[mi][ni] = __builtin_amdgcn_mfma_f32_16x16x32_bf16(af[mi], bf[ni * 2 + kk],
                                                                acc[mi][ni], 0, 0, 0);
    }
    __builtin_amdgcn_s_setprio(0);
  };

  bf16x8 bA[8], bB[8];
  // prologue: queue = [A(0) x4][B(0) x8]  (order pinned by sched_barrier fences)
  issueA(0, 0);
  __builtin_amdgcn_sched_barrier(0);
  loadB(bA, 0);
  __builtin_amdgcn_sched_barrier(0);

#pragma unroll
  for (int it = 0; it < NK / 2; ++it) {
    const int kt = 2 * it;
    // gate: newest 8 queue entries = B(kt); everything older (incl. A(kt)) retired
    asm volatile("s_waitcnt vmcnt(8)" ::: "memory");
    __builtin_amdgcn_s_barrier();
    __builtin_amdgcn_sched_barrier(0);
    if (kt + 1 < NK) {
      issueA(kt + 1, 1);
      __builtin_amdgcn_sched_barrier(0);
      loadB(bB, kt + 1);
      __builtin_amdgcn_sched_barrier(0);
    }
    compute(0, bA, kt);

    asm volatile("s_waitcnt vmcnt(8)" ::: "memory");
    __builtin_amdgcn_s_barrier();
    __builtin_amdgcn_sched_barrier(0);
    if (kt + 2 < NK) {
      issueA(kt + 2, 0);
      __builtin_amdgcn_sched_barrier(0);
      loadB(bA, kt + 2);
      __builtin_amdgcn_sched_barrier(0);
    }
    compute(1, bB, kt + 1);
  }

  // ---- partial BN stats: reduce over n within wave, unique slot — no atomics (R5 lesson)
  const int slot = (b * 32 + blockIdx.x) * 4 + wc;   // [0, 1024)
#pragma unroll
  for (int mi = 0; mi < 8; ++mi) {
    float s[4] = {0.f, 0.f, 0.f, 0.f}, q[4] = {0.f, 0.f, 0.f, 0.f};
#pragma unroll
    for (int ni = 0; ni < 4; ++ni)
#pragma unroll
      for (int r = 0; r < 4; ++r) { float v = acc[mi][ni][r]; s[r] += v; q[r] = fmaf(v, v, q[r]); }
#pragma unroll
    for (int m = 1; m <= 8; m <<= 1)
#pragma unroll
      for (int r = 0; r < 4; ++r) { s[r] += __shfl_xor(s[r], m); q[r] += __shfl_xor(q[r], m); }
    if ((l & 15) == 0) {
      int o = wr * 128 + mi * 16 + ((l >> 4) << 2);
#pragma unroll
      for (int r = 0; r < 4; ++r) {
        psum[(size_t)(o + r) * 1024 + slot] = s[r];
        psq [(size_t)(o + r) * 1024 + slot] = q[r];
      }
    }
  }

  // ---- C store, point-major (o contiguous): u16x4 per frag  [frag map m89-verified]
#pragma unroll
  for (int mi = 0; mi < 8; ++mi) {
    int o = wr * 128 + mi * 16 + ((l >> 4) << 2);
#pragma unroll
    for (int ni = 0; ni < 4; ++ni) {
      int n = n0 + wc * 64 + ni * 16 + (l & 15);
      u16x4 pk;
#pragma unroll
      for (int r = 0; r < 4; ++r) pk[r] = f2bf(acc[mi][ni][r]);
      *(u16x4*)(C + ((size_t)b * N_ + n) * 256 + o) = pk;
    }
  }
}

// ---------------- BN finalize: reduce 1024 partials per channel, compute scale/shift ----------------

__global__ __launch_bounds__(256) void k_finalize(const float* __restrict__ psum,
                                                  const float* __restrict__ psq,
                                                  const float* __restrict__ g,
                                                  const float* __restrict__ bb,
                                                  float* __restrict__ scale,
                                                  float* __restrict__ shift) {
  int c = blockIdx.x;
  const float* ps = psum + (size_t)c * 1024;
  const float* pq = psq + (size_t)c * 1024;
  float s = 0.f, q = 0.f;
#pragma unroll
  for (int k = 0; k < 4; ++k) { s += ps[threadIdx.x + 256 * k]; q += pq[threadIdx.x + 256 * k]; }
#pragma unroll
  for (int off = 32; off; off >>= 1) { s += __shfl_down(s, off); q += __shfl_down(q, off); }
  __shared__ float rs[4], rq[4];
  if ((threadIdx.x & 63) == 0) { rs[threadIdx.x >> 6] = s; rq[threadIdx.x >> 6] = q; }
  __syncthreads();
  if (threadIdx.x == 0) {
    float S = rs[0] + rs[1] + rs[2] + rs[3];
    float Q = rq[0] + rq[1] + rq[2] + rq[3];
    const float inv_n = 1.f / 65536.f;
    float mean = S * inv_n;
    float var = Q * inv_n - mean * mean;
    float rstd = rsqrtf(var + 1e-5f);
    float sc = g[c] * rstd;
    scale[c] = sc;
    shift[c] = bb[c] - mean * sc;
  }
}

// BN+ReLU + transpose: y2 point-major bf16 (b,n,256) -> d_out channel-major f32 (b,256,N)
__global__ void k_trbnout(const unsigned short* __restrict__ y, const float* __restrict__ scale,
                          const float* __restrict__ shift, float* __restrict__ out) {
  __shared__ float t[32][33];
  int b = blockIdx.z;
  int n0 = blockIdx.x * 32, c0 = blockIdx.y * 32;
  int tx = threadIdx.x, ty = threadIdx.y;
  float sc = scale[c0 + tx], sh = shift[c0 + tx];
#pragma unroll
  for (int i = 0; i < 32; i += 8) {
    float v = bf2f(y[((size_t)b * N_ + n0 + ty + i) * 256 + c0 + tx]);
    t[ty + i][tx] = fmaxf(v * sc + sh, 0.f);
  }
  __syncthreads();
  float* op = out + ((size_t)b * 256 + c0) * N_ + n0;
#pragma unroll
  for (int i = 0; i < 32; i += 8) op[(size_t)(ty + i) * N_ + tx] = t[tx][ty + i];
}

// ---------------- launch ----------------

extern "C" void kernel_launch(void* const* d_in, const int* in_sizes, int n_in,
                              void* d_out, int out_size, void* d_ws, size_t ws_size,
                              hipStream_t stream) {
  const float* unknown = (const float*)d_in[0];
  const float* known   = (const float*)d_in[1];
  const float* uf      = (const float*)d_in[2];
  const float* kf      = (const float*)d_in[3];
  const float* W1      = (const float*)d_in[4];
  const float* g1      = (const float*)d_in[5];
  const float* b1      = (const float*)d_in[6];
  const float* W2      = (const float*)d_in[7];
  const float* g2      = (const float*)d_in[8];
  const float* b2      = (const float*)d_in[9];
  float* out = (float*)d_out;

  char* ws = (char*)d_ws;
  unsigned short* xt  = (unsigned short*)(ws);                    // (B,N,768) bf16   100,663,296 B
  unsigned short* y1  = (unsigned short*)(ws + 100663296);        // (B,N,256) bf16    33,554,432 B
  unsigned short* y2  = (unsigned short*)(ws + 134217728);        // (B,N,256) bf16    33,554,432 B
  float*          kft = (float*)(ws + 167772160);                 // (B,M,512) f32     16,777,216 B
  // psum/psq alias kft's region: kft is dead after k_interp; both gemms reuse sequentially
  float*          psum = (float*)(ws + 167772160);                // 256*1024 f32       1,048,576 B
  float*          psq  = (float*)(ws + 168820736);                // 256*1024 f32       1,048,576 B
  unsigned short* w1b = (unsigned short*)(ws + 184549376);        //                      393,216 B
  unsigned short* w2b = (unsigned short*)(ws + 184942592);        //                      131,072 B
  int*            idx = (int*)(ws + 185073664);                   //                      786,432 B
  float*          wgt = (float*)(ws + 185860096);                 //                      786,432 B
  float*          st  = (float*)(ws + 186646528);                 // sc/sh block            4,096 B
  float *sc1 = st, *sh1 = st + 256, *sc2 = st + 512, *sh2 = st + 768;

  k_cast<<<768, 256, 0, stream>>>(W1, w1b, CMID_ * CIN_);
  k_cast<<<256, 256, 0, stream>>>(W2, w2b, COUT_ * CMID_);
  k_tr_kf<<<dim3(16, 32, B_), dim3(32, 8), 0, stream>>>(kf, kft);
  k_tr_uf<<<dim3(8, 256, B_), dim3(32, 8), 0, stream>>>(uf, xt);
  k_three_nn<<<B_ * 256, 256, 0, stream>>>(unknown, known, idx, wgt);
  k_interp<<<B_ * N_ / 8, 256, 0, stream>>>(kft, idx, wgt, xt);
  gemm256<CIN_, false><<<dim3(32, B_), 512, 0, stream>>>(w1b, xt, y1, psum, psq, nullptr, nullptr);
  k_finalize<<<256, 256, 0, stream>>>(psum, psq, g1, b1, sc1, sh1);
  gemm256<CMID_, true><<<dim3(32, B_), 512, 0, stream>>>(w2b, y1, y2, psum, psq, sc1, sh1);
  k_finalize<<<256, 256, 0, stream>>>(psum, psq, g2, b2, sc2, sh2);
  k_trbnout<<<dim3(256, 8, B_), dim3(32, 8), 0, stream>>>(y2, sc2, sh2, out);
}

// Round 8
// 205.783 us; speedup vs baseline: 1.1587x; 1.1587x over previous
//
#include <hip/hip_runtime.h>

#define B_    8
#define N_    8192
#define M_    1024
#define C1_   256
#define C2_   512
#define CIN_  768
#define CMID_ 256
#define COUT_ 256

typedef __attribute__((ext_vector_type(8))) __bf16 bf16x8;           // 4 VGPRs, MFMA A/B frag
typedef __attribute__((ext_vector_type(4))) float f32x4;             // MFMA C/D frag
typedef __attribute__((ext_vector_type(4))) unsigned short u16x4;
typedef __attribute__((ext_vector_type(8))) unsigned short u16x8;

__device__ __forceinline__ unsigned short f2bf(float f) {
  union { float f; unsigned u; } v; v.f = f;
  unsigned r = v.u + 0x7FFFu + ((v.u >> 16) & 1u);   // RNE
  return (unsigned short)(r >> 16);
}
__device__ __forceinline__ float bf2f(unsigned short h) {
  union { unsigned u; float f; } v; v.u = ((unsigned)h) << 16; return v.f;
}

// async global -> LDS, 16B per lane per wave-instruction (dest = uniform base + lane*16)
__device__ __forceinline__ void gload16(const void* g, void* l) {
  __builtin_amdgcn_global_load_lds((const __attribute__((address_space(1))) unsigned int*)g,
                                   (__attribute__((address_space(3))) unsigned int*)l, 16, 0, 0);
}

// ---------------- small utility kernels ----------------

__global__ void k_cast(const float* __restrict__ in, unsigned short* __restrict__ out, int n) {
  int i = blockIdx.x * 256 + threadIdx.x;
  if (i < n) out[i] = f2bf(in[i]);
}

// known_feats (B, C2, M) f32 -> kft (B, M, C2) f32
__global__ void k_tr_kf(const float* __restrict__ in, float* __restrict__ out) {
  __shared__ float t[32][33];
  int b = blockIdx.z;
  int c0 = blockIdx.x * 32, m0 = blockIdx.y * 32;
  int tx = threadIdx.x, ty = threadIdx.y;
  const float* ip = in + ((size_t)b * C2_ + c0) * M_ + m0;
#pragma unroll
  for (int i = 0; i < 32; i += 8) t[ty + i][tx] = ip[(size_t)(ty + i) * M_ + tx];
  __syncthreads();
  float* op = out + ((size_t)b * M_ + m0) * C2_ + c0;
#pragma unroll
  for (int i = 0; i < 32; i += 8) op[(size_t)(ty + i) * C2_ + tx] = t[tx][ty + i];
}

// unknow_feats (B, C1, N) f32 -> xt[b][n][0:256] bf16 (row stride CIN_)
__global__ void k_tr_uf(const float* __restrict__ in, unsigned short* __restrict__ out) {
  __shared__ float t[32][33];
  int b = blockIdx.z;
  int c0 = blockIdx.x * 32, n0 = blockIdx.y * 32;
  int tx = threadIdx.x, ty = threadIdx.y;
  const float* ip = in + ((size_t)b * C1_ + c0) * N_ + n0;
#pragma unroll
  for (int i = 0; i < 32; i += 8) t[ty + i][tx] = ip[(size_t)(ty + i) * N_ + tx];
  __syncthreads();
  unsigned short* op = out + ((size_t)b * N_ + n0) * CIN_ + c0;
#pragma unroll
  for (int i = 0; i < 32; i += 8) op[(size_t)(ty + i) * CIN_ + tx] = f2bf(t[tx][ty + i]);
}

// ---------------- three_nn: exact fp32 (d, idx)-lex semantics, 8 lanes/query ----------------

__device__ __forceinline__ void ins3(float db, int ib, float& d0, int& i0,
                                     float& d1, int& i1, float& d2, int& i2) {
  if (db < d2 || (db == d2 && ib < i2)) {
    if (db < d1 || (db == d1 && ib < i1)) {
      d2 = d1; i2 = i1;
      if (db < d0 || (db == d0 && ib < i0)) { d1 = d0; i1 = i0; d0 = db; i0 = ib; }
      else                                  { d1 = db; i1 = ib; }
    } else { d2 = db; i2 = ib; }
  }
}

__global__ __launch_bounds__(256) void k_three_nn(const float* __restrict__ unknown,
                                                  const float* __restrict__ known,
                                                  int* __restrict__ idx, float* __restrict__ wgt) {
  __shared__ __align__(16) float kpts[M_][4];
  int b = blockIdx.x >> 8;
  int n0 = (blockIdx.x & 255) << 5;
  for (int i = threadIdx.x; i < M_; i += 256) {
    const float* kp = known + ((size_t)b * M_ + i) * 3;
    kpts[i][0] = kp[0]; kpts[i][1] = kp[1]; kpts[i][2] = kp[2];
  }
  __syncthreads();
  const int l = threadIdx.x & 63;
  const int j = l & 7;
  const int q = ((threadIdx.x >> 6) << 3) + (l >> 3);
  const int n = n0 + q;
  const float* up = unknown + ((size_t)b * N_ + n) * 3;
  float ux = up[0], uy = up[1], uz = up[2];
  float d0 = 1e30f, d1 = 1e30f, d2v = 1e30f;
  int i0 = 0, i1 = 0, i2 = 0;
  for (int t = 0; t < 128; ++t) {
    int i = t * 8 + j;
    f32x4 p = *(const f32x4*)kpts[i];
    float dx = __fsub_rn(ux, p[0]);
    float dy = __fsub_rn(uy, p[1]);
    float dz = __fsub_rn(uz, p[2]);
    float d = __fadd_rn(__fadd_rn(__fmul_rn(dx, dx), __fmul_rn(dy, dy)), __fmul_rn(dz, dz));
    if (d < d2v) {
      if (d < d1) {
        if (d < d0) { d2v = d1; i2 = i1; d1 = d0; i1 = i0; d0 = d; i0 = i; }
        else        { d2v = d1; i2 = i1; d1 = d;  i1 = i; }
      } else        { d2v = d;  i2 = i; }
    }
  }
#pragma unroll
  for (int m = 1; m <= 4; m <<= 1) {
    float e0 = __shfl_xor(d0, m), e1 = __shfl_xor(d1, m), e2 = __shfl_xor(d2v, m);
    int   f0 = __shfl_xor(i0, m), f1 = __shfl_xor(i1, m), f2 = __shfl_xor(i2, m);
    ins3(e0, f0, d0, i0, d1, i1, d2v, i2);
    ins3(e1, f1, d0, i0, d1, i1, d2v, i2);
    ins3(e2, f2, d0, i0, d1, i1, d2v, i2);
  }
  if (j == 0) {
    float w0 = 1.f / (d0 + 1e-8f), w1 = 1.f / (d1 + 1e-8f), w2 = 1.f / (d2v + 1e-8f);
    float s = w0 + w1 + w2;
    size_t base = ((size_t)b * N_ + n) * 3;
    idx[base] = i0; idx[base + 1] = i1; idx[base + 2] = i2;
    wgt[base] = w0 / s; wgt[base + 1] = w1 / s; wgt[base + 2] = w2 / s;
  }
}

// interp -> xt[b][n][256:768] bf16; 8 points/block, 32 lanes each, float4 gathers
__global__ __launch_bounds__(256) void k_interp(const float* __restrict__ kft, const int* __restrict__ idx,
                                                const float* __restrict__ wgt, unsigned short* __restrict__ xt) {
  int pb = blockIdx.x * 8 + (threadIdx.x >> 5);
  int lane = threadIdx.x & 31;
  int b = pb >> 13;
  size_t t3 = (size_t)pb * 3;
  int i0 = idx[t3], i1 = idx[t3 + 1], i2 = idx[t3 + 2];
  float w0 = wgt[t3], w1 = wgt[t3 + 1], w2 = wgt[t3 + 2];
  const f32x4* f0 = (const f32x4*)(kft + ((size_t)b * M_ + i0) * C2_);
  const f32x4* f1 = (const f32x4*)(kft + ((size_t)b * M_ + i1) * C2_);
  const f32x4* f2 = (const f32x4*)(kft + ((size_t)b * M_ + i2) * C2_);
  unsigned short* o = xt + (size_t)pb * CIN_ + C1_;
#pragma unroll
  for (int k = 0; k < 4; ++k) {
    int c4 = lane + 32 * k;
    f32x4 a = f0[c4], bb = f1[c4], cc = f2[c4];
    u16x4 r;
#pragma unroll
    for (int e = 0; e < 4; ++e) r[e] = f2bf(w0 * a[e] + w1 * bb[e] + w2 * cc[e]);
    *(u16x4*)(o + 4 * c4) = r;
  }
}

// ---------------- bf16 MFMA GEMM, 2-phase dbuf, BK=32 for 4 blocks/CU ----------------
// C(256 x 8192) = A(256 x K) * X^T, X point-major (N x K).
// 128x128 tile, BK=32 (64-B k-rows), 4 waves (2x2), wave tile 64x64 = 4x4 frags, 16 MFMA/step.
// LDS: dbuf 2 x (A 8K + B 8K) = 32 KB; epilogue transpose tile reuses [0, 36864) (union);
// BN scale/shift cached at [32768, 34816) during the loop. Static total 36,864 B -> 4 blocks/CU
// (R6 at 64 KB was 2 blocks/CU; this round's single lever = 2x resident waves for drain overlap).
// Swizzle: LDS slot (row, j) holds global granule j ^ ((row>>1)&3) (16-B granules, 4/row).
//   Worst-case bank aliasing 2-way = free (m136). gload_lds: linear dest + pre-swizzled
//   global source (rule 21); BN path: reg-stage B + ds_write to swizzled slot.
// Schedule per K-step: issue STAGE(kt+1 -> buf^1) -> compute(kt) -> [bnwrite kt+1] -> barrier.
// Stats epilogue: per-block partials to unique slots (no atomics, R5 lesson).
// EPI 0: out point-major bf16 (ld=256).  EPI 1: out channel-major bf16 (ld=N_).

template <int K, int EPI, bool BN>
__global__ __launch_bounds__(256, 4) void gemm_bt(const unsigned short* __restrict__ A,
                                                  const unsigned short* __restrict__ Bm,
                                                  unsigned short* __restrict__ C,
                                                  float* __restrict__ psum, float* __restrict__ psq,
                                                  const float* __restrict__ scale,
                                                  const float* __restrict__ shift) {
  __shared__ __align__(16) char lds[36864];   // dbuf [0,32K); lsc/lsh [32K,34K); epi tile [0,36864)
  float* lsc = (float*)(lds + 32768);
  float* lsh = (float*)(lds + 33792);
  const int tid = threadIdx.x;
  const int l = tid & 63;
  const int wv = tid >> 6;
  const int wr = wv >> 1, wc = wv & 1;
  const int b = blockIdx.z;
  const int o0 = blockIdx.y * 128;
  const int n0 = blockIdx.x * 128;
  const char* Ab = (const char*)A + (size_t)o0 * (K * 2);
  const char* Bb = (const char*)Bm + ((size_t)b * N_ + n0) * (K * 2);

  if (BN) {
    lsc[tid] = scale[tid]; lsh[tid] = shift[tid];
    __syncthreads();                       // lsc/lsh visible to all waves before first bnwrite
  }

  f32x4 acc[4][4];
#pragma unroll
  for (int i = 0; i < 4; ++i)
#pragma unroll
    for (int j = 0; j < 4; ++j) acc[i][j] = f32x4{0.f, 0.f, 0.f, 0.f};

  // gload geometry: wave wv stages rows wv*32 + i*16 + (l>>2), i in {0,1}; granule l&3.
  // Linear LDS dest lane slot; global source granule pre-swizzled: (l&3) ^ ((l>>3)&3).
  const int grow = wv * 32 + (l >> 2);                 // + i*16
  const int gcol = ((l & 3) ^ ((l >> 3) & 3)) * 16;
  // reg-staging geometry (BN path): 2 chunks of 16B per thread; chunk q: row=q>>2, g=q&3
  int srow[2], sg[2];
#pragma unroll
  for (int i = 0; i < 2; ++i) { int q = tid + i * 256; srow[i] = q >> 2; sg[i] = q & 3; }

  auto issueA = [&](int kt, char* buf) {
#pragma unroll
    for (int i = 0; i < 2; ++i)
      gload16(Ab + (size_t)(grow + i * 16) * (K * 2) + kt * 64 + gcol,
              buf + wv * 2048 + i * 1024);
  };
  auto issueB = [&](int kt, char* buf) {
#pragma unroll
    for (int i = 0; i < 2; ++i)
      gload16(Bb + (size_t)(grow + i * 16) * (K * 2) + kt * 64 + gcol,
              buf + 8192 + wv * 2048 + i * 1024);
  };
  auto loadBreg = [&](bf16x8* rb, int kt) {
#pragma unroll
    for (int i = 0; i < 2; ++i)
      rb[i] = *(const bf16x8*)(Bb + (size_t)srow[i] * (K * 2) + kt * 64 + sg[i] * 16);
  };
  auto bnwrite = [&](bf16x8* rb, int kt, char* buf) {
#pragma unroll
    for (int i = 0; i < 2; ++i) {
      u16x8 v = *(u16x8*)&rb[i];
      int c0 = kt * 32 + sg[i] * 8;
      u16x8 r;
#pragma unroll
      for (int e = 0; e < 8; ++e)
        r[e] = f2bf(fmaxf(bf2f(v[e]) * lsc[c0 + e] + lsh[c0 + e], 0.f));
      *(u16x8*)(buf + 8192 + srow[i] * 64 + (sg[i] ^ ((srow[i] >> 1) & 3)) * 16) = r;
    }
  };

  // ---- prologue: stage kt=0 into buffer 0
  if (BN) {
    bf16x8 rb0[2];
    loadBreg(rb0, 0);
    issueA(0, lds);
    bnwrite(rb0, 0, lds);
  } else {
    issueA(0, lds);
    issueB(0, lds);
  }
  __syncthreads();

  // ---- main loop: one barrier per K-step (BK=32, 16 MFMA)
  const int NK = K / 32;
  int cur = 0;
  for (int kt = 0; kt < NK; ++kt) {
    const bool haveNext = (kt + 1 < NK);
    char* nb = lds + (cur ^ 1) * 16384;
    bf16x8 rb2[2];
    if (haveNext) {
      if (BN) { loadBreg(rb2, kt + 1); issueA(kt + 1, nb); }
      else    { issueA(kt + 1, nb); issueB(kt + 1, nb); }
    }
    // compute on buf[cur]
    const char* base = lds + cur * 16384;
    bf16x8 af[4], bfr[4];
#pragma unroll
    for (int mi = 0; mi < 4; ++mi) {
      int row = wr * 64 + mi * 16 + (l & 15);
      int g = (l >> 4) ^ ((row >> 1) & 3);
      af[mi] = *(const bf16x8*)(base + row * 64 + g * 16);
    }
#pragma unroll
    for (int ni = 0; ni < 4; ++ni) {
      int row = wc * 64 + ni * 16 + (l & 15);
      int g = (l >> 4) ^ ((row >> 1) & 3);
      bfr[ni] = *(const bf16x8*)(base + 8192 + row * 64 + g * 16);
    }
#pragma unroll
    for (int mi = 0; mi < 4; ++mi)
#pragma unroll
      for (int ni = 0; ni < 4; ++ni)
        acc[mi][ni] = __builtin_amdgcn_mfma_f32_16x16x32_bf16(af[mi], bfr[ni], acc[mi][ni], 0, 0, 0);
    if (BN && haveNext) bnwrite(rb2, kt + 1, nb);
    __syncthreads();   // drains vmcnt (next-tile gloads) + lgkm before buffer flip
    cur ^= 1;
  }

  // ---- partial BN stats: reduce over n within wave, unique slot — no atomics (R5 lesson)
  const int slot = (blockIdx.z * 64 + blockIdx.x) * 2 + wc;   // [0, 1024)
#pragma unroll
  for (int mi = 0; mi < 4; ++mi) {
    float s[4] = {0.f, 0.f, 0.f, 0.f}, q[4] = {0.f, 0.f, 0.f, 0.f};
#pragma unroll
    for (int ni = 0; ni < 4; ++ni)
#pragma unroll
      for (int r = 0; r < 4; ++r) { float v = acc[mi][ni][r]; s[r] += v; q[r] = fmaf(v, v, q[r]); }
#pragma unroll
    for (int m = 1; m <= 8; m <<= 1)
#pragma unroll
      for (int r = 0; r < 4; ++r) { s[r] += __shfl_xor(s[r], m); q[r] += __shfl_xor(q[r], m); }
    if ((l & 15) == 0) {
      int o = o0 + wr * 64 + mi * 16 + ((l >> 4) << 2);
#pragma unroll
      for (int r = 0; r < 4; ++r) {
        psum[(size_t)(o + r) * 1024 + slot] = s[r];
        psq [(size_t)(o + r) * 1024 + slot] = q[r];
      }
    }
  }

  // ---- transposing epilogue: acc -> LDS tile [128][144 u16] -> 256-B contiguous stores
  // (final loop barrier precedes; lsc/lsh are dead by now — region reused)
  unsigned short* t16 = (unsigned short*)lds;
#pragma unroll
  for (int mi = 0; mi < 4; ++mi) {
    int ol = wr * 64 + mi * 16 + ((l >> 4) << 2);
#pragma unroll
    for (int ni = 0; ni < 4; ++ni) {
      int nl = wc * 64 + ni * 16 + (l & 15);
#pragma unroll
      for (int r = 0; r < 4; ++r) {
        unsigned short v = f2bf(acc[mi][ni][r]);
        if (EPI == 0) t16[nl * 144 + ol + r] = v;        // rows = points   (y1 point-major)
        else          t16[(ol + r) * 144 + nl] = v;      // rows = channels (y2 channel-major)
      }
    }
  }
  __syncthreads();
#pragma unroll
  for (int t = 0; t < 8; ++t) {
    int row = wv * 32 + (l >> 4) + t * 4;
    u16x8 v = *(const u16x8*)(t16 + row * 144 + (l & 15) * 8);
    if (EPI == 0)
      *(u16x8*)(C + ((size_t)b * N_ + n0 + row) * 256 + o0 + (l & 15) * 8) = v;
    else
      *(u16x8*)(C + ((size_t)b * 256 + o0 + row) * N_ + n0 + (l & 15) * 8) = v;
  }
}

// ---------------- BN finalize: reduce 1024 partials per channel, compute scale/shift ----------------

__global__ __launch_bounds__(256) void k_finalize(const float* __restrict__ psum,
                                                  const float* __restrict__ psq,
                                                  const float* __restrict__ g,
                                                  const float* __restrict__ bb,
                                                  float* __restrict__ scale,
                                                  float* __restrict__ shift) {
  int c = blockIdx.x;
  const float* ps = psum + (size_t)c * 1024;
  const float* pq = psq + (size_t)c * 1024;
  float s = 0.f, q = 0.f;
#pragma unroll
  for (int k = 0; k < 4; ++k) { s += ps[threadIdx.x + 256 * k]; q += pq[threadIdx.x + 256 * k]; }
#pragma unroll
  for (int off = 32; off; off >>= 1) { s += __shfl_down(s, off); q += __shfl_down(q, off); }
  __shared__ float rs[4], rq[4];
  if ((threadIdx.x & 63) == 0) { rs[threadIdx.x >> 6] = s; rq[threadIdx.x >> 6] = q; }
  __syncthreads();
  if (threadIdx.x == 0) {
    float S = rs[0] + rs[1] + rs[2] + rs[3];
    float Q = rq[0] + rq[1] + rq[2] + rq[3];
    const float inv_n = 1.f / 65536.f;
    float mean = S * inv_n;
    float var = Q * inv_n - mean * mean;
    float rstd = rsqrtf(var + 1e-5f);
    float sc = g[c] * rstd;
    scale[c] = sc;
    shift[c] = bb[c] - mean * sc;
  }
}

// BN+ReLU on channel-major bf16 -> fp32 d_out
__global__ void k_bnrelu_out(const unsigned short* __restrict__ y, const float* __restrict__ scale,
                             const float* __restrict__ shift, float* __restrict__ out) {
  size_t i = ((size_t)blockIdx.x * 256 + threadIdx.x) * 4;
  int c = (int)((i >> 13) & 255);
  float sc = scale[c], sh = shift[c];
  u16x4 v = *(const u16x4*)(y + i);
  f32x4 o;
#pragma unroll
  for (int k = 0; k < 4; ++k) o[k] = fmaxf(bf2f(v[k]) * sc + sh, 0.f);
  *(f32x4*)(out + i) = o;
}

// ---------------- launch ----------------

extern "C" void kernel_launch(void* const* d_in, const int* in_sizes, int n_in,
                              void* d_out, int out_size, void* d_ws, size_t ws_size,
                              hipStream_t stream) {
  const float* unknown = (const float*)d_in[0];
  const float* known   = (const float*)d_in[1];
  const float* uf      = (const float*)d_in[2];
  const float* kf      = (const float*)d_in[3];
  const float* W1      = (const float*)d_in[4];
  const float* g1      = (const float*)d_in[5];
  const float* b1      = (const float*)d_in[6];
  const float* W2      = (const float*)d_in[7];
  const float* g2      = (const float*)d_in[8];
  const float* b2      = (const float*)d_in[9];
  float* out = (float*)d_out;

  char* ws = (char*)d_ws;
  unsigned short* xt  = (unsigned short*)(ws);                    // (B,N,768) bf16   100,663,296 B
  unsigned short* y1  = (unsigned short*)(ws + 100663296);        // (B,N,256) bf16    33,554,432 B
  unsigned short* y2  = (unsigned short*)(ws + 134217728);        // (B,256,N) bf16    33,554,432 B
  float*          kft = (float*)(ws + 167772160);                 // (B,M,512) f32     16,777,216 B
  // psum/psq alias kft's region: kft is dead after k_interp; both gemms reuse sequentially
  float*          psum = (float*)(ws + 167772160);                // 256*1024 f32       1,048,576 B
  float*          psq  = (float*)(ws + 168820736);                // 256*1024 f32       1,048,576 B
  unsigned short* w1b = (unsigned short*)(ws + 184549376);        //                      393,216 B
  unsigned short* w2b = (unsigned short*)(ws + 184942592);        //                      131,072 B
  int*            idx = (int*)(ws + 185073664);                   //                      786,432 B
  float*          wgt = (float*)(ws + 185860096);                 //                      786,432 B
  float*          st  = (float*)(ws + 186646528);                 // sc/sh block            4,096 B
  float *sc1 = st, *sh1 = st + 256, *sc2 = st + 512, *sh2 = st + 768;

  k_cast<<<768, 256, 0, stream>>>(W1, w1b, CMID_ * CIN_);
  k_cast<<<256, 256, 0, stream>>>(W2, w2b, COUT_ * CMID_);
  k_tr_kf<<<dim3(16, 32, B_), dim3(32, 8), 0, stream>>>(kf, kft);
  k_tr_uf<<<dim3(8, 256, B_), dim3(32, 8), 0, stream>>>(uf, xt);
  k_three_nn<<<B_ * 256, 256, 0, stream>>>(unknown, known, idx, wgt);
  k_interp<<<B_ * N_ / 8, 256, 0, stream>>>(kft, idx, wgt, xt);
  gemm_bt<CIN_, 0, false><<<dim3(64, 2, B_), 256, 0, stream>>>(w1b, xt, y1, psum, psq, nullptr, nullptr);
  k_finalize<<<256, 256, 0, stream>>>(psum, psq, g1, b1, sc1, sh1);
  gemm_bt<CMID_, 1, true><<<dim3(64, 2, B_), 256, 0, stream>>>(w2b, y1, y2, psum, psq, sc1, sh1);
  k_finalize<<<256, 256, 0, stream>>>(psum, psq, g2, b2, sc2, sh2);
  k_bnrelu_out<<<16384, 256, 0, stream>>>(y2, sc2, sh2, out);
}

// Round 11
// 198.001 us; speedup vs baseline: 1.2042x; 1.0393x over previous
//
#include <hip/hip_runtime.h>

#define B_    8
#define N_    8192
#define M_    1024
#define C1_   256
#define C2_   512
#define CIN_  768
#define CMID_ 256
#define COUT_ 256

typedef __attribute__((ext_vector_type(8))) __bf16 bf16x8;           // 4 VGPRs, MFMA A/B frag
typedef __attribute__((ext_vector_type(4))) float f32x4;             // MFMA C/D frag
typedef __attribute__((ext_vector_type(4))) unsigned short u16x4;
typedef __attribute__((ext_vector_type(8))) unsigned short u16x8;

__device__ __forceinline__ unsigned short f2bf(float f) {
  union { float f; unsigned u; } v; v.f = f;
  unsigned r = v.u + 0x7FFFu + ((v.u >> 16) & 1u);   // RNE
  return (unsigned short)(r >> 16);
}
__device__ __forceinline__ float bf2f(unsigned short h) {
  union { unsigned u; float f; } v; v.u = ((unsigned)h) << 16; return v.f;
}

// async global -> LDS, 16B per lane per wave-instruction (dest = uniform base + lane*16)
__device__ __forceinline__ void gload16(const void* g, void* l) {
  __builtin_amdgcn_global_load_lds((const __attribute__((address_space(1))) unsigned int*)g,
                                   (__attribute__((address_space(3))) unsigned int*)l, 16, 0, 0);
}

// ---------------- small utility kernels ----------------

__global__ void k_cast(const float* __restrict__ in, unsigned short* __restrict__ out, int n) {
  int i = blockIdx.x * 256 + threadIdx.x;
  if (i < n) out[i] = f2bf(in[i]);
}

// known_feats (B, C2, M) f32 -> kft (B, M, C2) f32
__global__ void k_tr_kf(const float* __restrict__ in, float* __restrict__ out) {
  __shared__ float t[32][33];
  int b = blockIdx.z;
  int c0 = blockIdx.x * 32, m0 = blockIdx.y * 32;
  int tx = threadIdx.x, ty = threadIdx.y;
  const float* ip = in + ((size_t)b * C2_ + c0) * M_ + m0;
#pragma unroll
  for (int i = 0; i < 32; i += 8) t[ty + i][tx] = ip[(size_t)(ty + i) * M_ + tx];
  __syncthreads();
  float* op = out + ((size_t)b * M_ + m0) * C2_ + c0;
#pragma unroll
  for (int i = 0; i < 32; i += 8) op[(size_t)(ty + i) * C2_ + tx] = t[tx][ty + i];
}

// unknow_feats (B, C1, N) f32 -> xt[b][n][0:256] bf16 (row stride CIN_)
__global__ void k_tr_uf(const float* __restrict__ in, unsigned short* __restrict__ out) {
  __shared__ float t[32][33];
  int b = blockIdx.z;
  int c0 = blockIdx.x * 32, n0 = blockIdx.y * 32;
  int tx = threadIdx.x, ty = threadIdx.y;
  const float* ip = in + ((size_t)b * C1_ + c0) * N_ + n0;
#pragma unroll
  for (int i = 0; i < 32; i += 8) t[ty + i][tx] = ip[(size_t)(ty + i) * N_ + tx];
  __syncthreads();
  unsigned short* op = out + ((size_t)b * N_ + n0) * CIN_ + c0;
#pragma unroll
  for (int i = 0; i < 32; i += 8) op[(size_t)(ty + i) * CIN_ + tx] = f2bf(t[tx][ty + i]);
}

// ---------------- three_nn: exact fp32 (d, idx)-lex semantics, 8 lanes/query ----------------

__device__ __forceinline__ void ins3(float db, int ib, float& d0, int& i0,
                                     float& d1, int& i1, float& d2, int& i2) {
  if (db < d2 || (db == d2 && ib < i2)) {
    if (db < d1 || (db == d1 && ib < i1)) {
      d2 = d1; i2 = i1;
      if (db < d0 || (db == d0 && ib < i0)) { d1 = d0; i1 = i0; d0 = db; i0 = ib; }
      else                                  { d1 = db; i1 = ib; }
    } else { d2 = db; i2 = ib; }
  }
}

__global__ __launch_bounds__(256) void k_three_nn(const float* __restrict__ unknown,
                                                  const float* __restrict__ known,
                                                  int* __restrict__ idx, float* __restrict__ wgt) {
  __shared__ __align__(16) float kpts[M_][4];
  int b = blockIdx.x >> 8;
  int n0 = (blockIdx.x & 255) << 5;
  for (int i = threadIdx.x; i < M_; i += 256) {
    const float* kp = known + ((size_t)b * M_ + i) * 3;
    kpts[i][0] = kp[0]; kpts[i][1] = kp[1]; kpts[i][2] = kp[2];
  }
  __syncthreads();
  const int l = threadIdx.x & 63;
  const int j = l & 7;
  const int q = ((threadIdx.x >> 6) << 3) + (l >> 3);
  const int n = n0 + q;
  const float* up = unknown + ((size_t)b * N_ + n) * 3;
  float ux = up[0], uy = up[1], uz = up[2];
  float d0 = 1e30f, d1 = 1e30f, d2v = 1e30f;
  int i0 = 0, i1 = 0, i2 = 0;
  for (int t = 0; t < 128; ++t) {
    int i = t * 8 + j;
    f32x4 p = *(const f32x4*)kpts[i];
    float dx = __fsub_rn(ux, p[0]);
    float dy = __fsub_rn(uy, p[1]);
    float dz = __fsub_rn(uz, p[2]);
    float d = __fadd_rn(__fadd_rn(__fmul_rn(dx, dx), __fmul_rn(dy, dy)), __fmul_rn(dz, dz));
    if (d < d2v) {
      if (d < d1) {
        if (d < d0) { d2v = d1; i2 = i1; d1 = d0; i1 = i0; d0 = d; i0 = i; }
        else        { d2v = d1; i2 = i1; d1 = d;  i1 = i; }
      } else        { d2v = d;  i2 = i; }
    }
  }
#pragma unroll
  for (int m = 1; m <= 4; m <<= 1) {
    float e0 = __shfl_xor(d0, m), e1 = __shfl_xor(d1, m), e2 = __shfl_xor(d2v, m);
    int   f0 = __shfl_xor(i0, m), f1 = __shfl_xor(i1, m), f2 = __shfl_xor(i2, m);
    ins3(e0, f0, d0, i0, d1, i1, d2v, i2);
    ins3(e1, f1, d0, i0, d1, i1, d2v, i2);
    ins3(e2, f2, d0, i0, d1, i1, d2v, i2);
  }
  if (j == 0) {
    float w0 = 1.f / (d0 + 1e-8f), w1 = 1.f / (d1 + 1e-8f), w2 = 1.f / (d2v + 1e-8f);
    float s = w0 + w1 + w2;
    size_t base = ((size_t)b * N_ + n) * 3;
    idx[base] = i0; idx[base + 1] = i1; idx[base + 2] = i2;
    wgt[base] = w0 / s; wgt[base + 1] = w1 / s; wgt[base + 2] = w2 / s;
  }
}

// interp -> xt[b][n][256:768] bf16; 8 points/block, 32 lanes each, float4 gathers
__global__ __launch_bounds__(256) void k_interp(const float* __restrict__ kft, const int* __restrict__ idx,
                                                const float* __restrict__ wgt, unsigned short* __restrict__ xt) {
  int pb = blockIdx.x * 8 + (threadIdx.x >> 5);
  int lane = threadIdx.x & 31;
  int b = pb >> 13;
  size_t t3 = (size_t)pb * 3;
  int i0 = idx[t3], i1 = idx[t3 + 1], i2 = idx[t3 + 2];
  float w0 = wgt[t3], w1 = wgt[t3 + 1], w2 = wgt[t3 + 2];
  const f32x4* f0 = (const f32x4*)(kft + ((size_t)b * M_ + i0) * C2_);
  const f32x4* f1 = (const f32x4*)(kft + ((size_t)b * M_ + i1) * C2_);
  const f32x4* f2 = (const f32x4*)(kft + ((size_t)b * M_ + i2) * C2_);
  unsigned short* o = xt + (size_t)pb * CIN_ + C1_;
#pragma unroll
  for (int k = 0; k < 4; ++k) {
    int c4 = lane + 32 * k;
    f32x4 a = f0[c4], bb = f1[c4], cc = f2[c4];
    u16x4 r;
#pragma unroll
    for (int e = 0; e < 4; ++e) r[e] = f2bf(w0 * a[e] + w1 * bb[e] + w2 * cc[e]);
    *(u16x4*)(o + 4 * c4) = r;
  }
}

// ---------------- bf16 MFMA GEMM: BM=256 (full channel dim), R8-proven 2-phase dbuf ----------
// C(256 x 8192) = A(256 x K) * X^T, X point-major (N x K).
// 256x128 tile, BK=32, 4 waves (2o x 2n), wave tile 128x64: af[8] x bfr[4], 32 MFMA/step.
// WHY BM=256 (R10 post-mortem): with o0 in {0,128}, every B row-panel was fetched TWICE;
// staged-byte demand ~7 TB/s was the binding limit (gemm time tracked staged bytes, not
// FLOPs or steps). Full-channel blocks read each B byte once -> B demand halves.
// Sync structure byte-equivalent to R8 (PROVEN GREEN): 2-phase double buffer, stage kt+1
// then compute kt, ONE __syncthreads() (vmcnt+lgkm drain) per K-step. No counted vmcnt
// (R9/R10's counted triple-buffer failed correctness twice; abandoned).
// LDS: 2 bufs x (A 16K + B 8K) = 48 KB; lsc/lsh at 49152; total 51200 -> 2 blocks/CU (VGPR-capped).
// Swizzle (R5/R8-proven): LDS slot (row, g) holds global granule g ^ ((row>>1)&3);
//   gload_lds = linear dest + pre-swizzled global source; BN regB path swizzles at ds_write.
// Stats epilogue: per-block partials to unique slots (no atomics, R5 lesson).
// C-write: R8's transposing LDS epilogue run as TWO o-half passes ([128][144] u16 tile each).
// EPI 0: out point-major bf16 (ld=256).  EPI 1: out channel-major bf16 (ld=N_).

template <int K, int EPI, bool BN>
__global__ __launch_bounds__(256, 2) void gemm_bt(const unsigned short* __restrict__ A,
                                                  const unsigned short* __restrict__ Bm,
                                                  unsigned short* __restrict__ C,
                                                  float* __restrict__ psum, float* __restrict__ psq,
                                                  const float* __restrict__ scale,
                                                  const float* __restrict__ shift) {
  __shared__ __align__(16) char lds[51200];   // bufs [0,49152): 2 x 24K; lsc/lsh [49152,51200)
  float* lsc = (float*)(lds + 49152);
  float* lsh = (float*)(lds + 50176);
  const int tid = threadIdx.x;
  const int l = tid & 63;
  const int wv = tid >> 6;
  const int wr = wv >> 1, wc = wv & 1;     // wr: o-half (128 wide), wc: n-half (64 wide)
  const int b = blockIdx.y;
  const int n0 = blockIdx.x * 128;
  const char* Ab = (const char*)A;                                   // full 256-channel panel
  const char* Bb = (const char*)Bm + ((size_t)b * N_ + n0) * (K * 2);

  if (BN) {
    lsc[tid] = scale[tid]; lsh[tid] = shift[tid];
    __syncthreads();                       // lsc/lsh visible before first bnwrite
  }

  f32x4 acc[8][4];
#pragma unroll
  for (int i = 0; i < 8; ++i)
#pragma unroll
    for (int j = 0; j < 4; ++j) acc[i][j] = f32x4{0.f, 0.f, 0.f, 0.f};

  // gload geometry: each instr covers 16 rows x 64 B (lane l -> row +(l>>2), granule l&3).
  // Linear LDS dest; global source granule pre-swizzled: (l&3) ^ ((l>>3)&3)  [key=(row>>1)&3].
  const int gcol = ((l & 3) ^ ((l >> 3) & 3)) * 16;
  // reg-staging geometry (BN path): 2 chunks of 16B per thread; chunk q: row=q>>2, g=q&3
  int srow[2], sg[2];
#pragma unroll
  for (int i = 0; i < 2; ++i) { int q = tid + i * 256; srow[i] = q >> 2; sg[i] = q & 3; }

  auto issueA = [&](int kt, char* buf) {     // A tile: 256 rows x 64 B = 16 KB, 4 instr/wave
#pragma unroll
    for (int i = 0; i < 4; ++i)
      gload16(Ab + (size_t)(wv * 64 + i * 16 + (l >> 2)) * (K * 2) + kt * 64 + gcol,
              buf + wv * 4096 + i * 1024);
  };
  auto issueB = [&](int kt, char* buf) {     // B tile: 128 rows x 64 B = 8 KB, 2 instr/wave
#pragma unroll
    for (int i = 0; i < 2; ++i)
      gload16(Bb + (size_t)(wv * 32 + i * 16 + (l >> 2)) * (K * 2) + kt * 64 + gcol,
              buf + 16384 + wv * 2048 + i * 1024);
  };
  auto loadBreg = [&](bf16x8* rb, int kt) {
#pragma unroll
    for (int i = 0; i < 2; ++i)
      rb[i] = *(const bf16x8*)(Bb + (size_t)srow[i] * (K * 2) + kt * 64 + sg[i] * 16);
  };
  auto bnwrite = [&](bf16x8* rb, int kt, char* buf) {
#pragma unroll
    for (int i = 0; i < 2; ++i) {
      u16x8 v = *(u16x8*)&rb[i];
      int c0 = kt * 32 + sg[i] * 8;
      u16x8 r;
#pragma unroll
      for (int e = 0; e < 8; ++e)
        r[e] = f2bf(fmaxf(bf2f(v[e]) * lsc[c0 + e] + lsh[c0 + e], 0.f));
      *(u16x8*)(buf + 16384 + srow[i] * 64 + (sg[i] ^ ((srow[i] >> 1) & 3)) * 16) = r;
    }
  };

  // ---- prologue: stage kt=0 into buffer 0 (R8-proven order)
  if (BN) {
    bf16x8 rb0[2];
    loadBreg(rb0, 0);
    issueA(0, lds);
    bnwrite(rb0, 0, lds);
  } else {
    issueA(0, lds);
    issueB(0, lds);
  }
  __syncthreads();

  // ---- main loop: one barrier per K-step (32 MFMA/step)
  const int NK = K / 32;
  int cur = 0;
  for (int kt = 0; kt < NK; ++kt) {
    const bool haveNext = (kt + 1 < NK);
    char* nb = lds + (cur ^ 1) * 24576;
    bf16x8 rb2[2];
    if (haveNext) {
      if (BN) { loadBreg(rb2, kt + 1); issueA(kt + 1, nb); }
      else    { issueA(kt + 1, nb); issueB(kt + 1, nb); }
    }
    // compute on buf[cur]
    const char* base = lds + cur * 24576;
    bf16x8 af[8], bfr[4];
#pragma unroll
    for (int mi = 0; mi < 8; ++mi) {
      int row = wr * 128 + mi * 16 + (l & 15);
      int g = (l >> 4) ^ ((row >> 1) & 3);
      af[mi] = *(const bf16x8*)(base + row * 64 + g * 16);
    }
#pragma unroll
    for (int ni = 0; ni < 4; ++ni) {
      int row = wc * 64 + ni * 16 + (l & 15);
      int g = (l >> 4) ^ ((row >> 1) & 3);
      bfr[ni] = *(const bf16x8*)(base + 16384 + row * 64 + g * 16);
    }
#pragma unroll
    for (int mi = 0; mi < 8; ++mi)
#pragma unroll
      for (int ni = 0; ni < 4; ++ni)
        acc[mi][ni] = __builtin_amdgcn_mfma_f32_16x16x32_bf16(af[mi], bfr[ni], acc[mi][ni], 0, 0, 0);
    if (BN && haveNext) bnwrite(rb2, kt + 1, nb);
    __syncthreads();   // drains vmcnt (next-tile gloads) + lgkm before buffer flip
    cur ^= 1;
  }

  // ---- partial BN stats: reduce over n within wave, unique slot — no atomics (R5 lesson)
  const int slot = (b * 64 + blockIdx.x) * 2 + wc;   // [0, 1024)
#pragma unroll
  for (int mi = 0; mi < 8; ++mi) {
    float s[4] = {0.f, 0.f, 0.f, 0.f}, q[4] = {0.f, 0.f, 0.f, 0.f};
#pragma unroll
    for (int ni = 0; ni < 4; ++ni)
#pragma unroll
      for (int r = 0; r < 4; ++r) { float v = acc[mi][ni][r]; s[r] += v; q[r] = fmaf(v, v, q[r]); }
#pragma unroll
    for (int m = 1; m <= 8; m <<= 1)
#pragma unroll
      for (int r = 0; r < 4; ++r) { s[r] += __shfl_xor(s[r], m); q[r] += __shfl_xor(q[r], m); }
    if ((l & 15) == 0) {
      int o = wr * 128 + mi * 16 + ((l >> 4) << 2);
#pragma unroll
      for (int r = 0; r < 4; ++r) {
        psum[(size_t)(o + r) * 1024 + slot] = s[r];
        psq [(size_t)(o + r) * 1024 + slot] = q[r];
      }
    }
  }

  // ---- transposing epilogue, two o-half passes (R8's proven [128][144] tile per pass)
  unsigned short* t16 = (unsigned short*)lds;
#pragma unroll
  for (int p = 0; p < 2; ++p) {
    __syncthreads();                       // prior ds_reads / prior pass stores complete
    if (wr == p) {
#pragma unroll
      for (int mi = 0; mi < 8; ++mi) {
        int ol = mi * 16 + ((l >> 4) << 2);         // o within half [0,128)
#pragma unroll
        for (int ni = 0; ni < 4; ++ni) {
          int nl = wc * 64 + ni * 16 + (l & 15);    // n within tile [0,128)
#pragma unroll
          for (int r = 0; r < 4; ++r) {
            unsigned short v = f2bf(acc[mi][ni][r]);
            if (EPI == 0) t16[nl * 144 + ol + r] = v;     // rows = points
            else          t16[(ol + r) * 144 + nl] = v;   // rows = channels
          }
        }
      }
    }
    __syncthreads();
#pragma unroll
    for (int t = 0; t < 8; ++t) {
      int row = wv * 32 + (l >> 4) + t * 4;         // [0,128)
      u16x8 v = *(const u16x8*)(t16 + row * 144 + (l & 15) * 8);
      if (EPI == 0)
        *(u16x8*)(C + ((size_t)b * N_ + n0 + row) * 256 + p * 128 + (l & 15) * 8) = v;
      else
        *(u16x8*)(C + ((size_t)b * 256 + p * 128 + row) * N_ + n0 + (l & 15) * 8) = v;
    }
  }
}

// ---------------- BN finalize: reduce 1024 partials per channel, compute scale/shift ----------------

__global__ __launch_bounds__(256) void k_finalize(const float* __restrict__ psum,
                                                  const float* __restrict__ psq,
                                                  const float* __restrict__ g,
                                                  const float* __restrict__ bb,
                                                  float* __restrict__ scale,
                                                  float* __restrict__ shift) {
  int c = blockIdx.x;
  const float* ps = psum + (size_t)c * 1024;
  const float* pq = psq + (size_t)c * 1024;
  float s = 0.f, q = 0.f;
#pragma unroll
  for (int k = 0; k < 4; ++k) { s += ps[threadIdx.x + 256 * k]; q += pq[threadIdx.x + 256 * k]; }
#pragma unroll
  for (int off = 32; off; off >>= 1) { s += __shfl_down(s, off); q += __shfl_down(q, off); }
  __shared__ float rs[4], rq[4];
  if ((threadIdx.x & 63) == 0) { rs[threadIdx.x >> 6] = s; rq[threadIdx.x >> 6] = q; }
  __syncthreads();
  if (threadIdx.x == 0) {
    float S = rs[0] + rs[1] + rs[2] + rs[3];
    float Q = rq[0] + rq[1] + rq[2] + rq[3];
    const float inv_n = 1.f / 65536.f;
    float mean = S * inv_n;
    float var = Q * inv_n - mean * mean;
    float rstd = rsqrtf(var + 1e-5f);
    float sc = g[c] * rstd;
    scale[c] = sc;
    shift[c] = bb[c] - mean * sc;
  }
}

// BN+ReLU on channel-major bf16 -> fp32 d_out
__global__ void k_bnrelu_out(const unsigned short* __restrict__ y, const float* __restrict__ scale,
                             const float* __restrict__ shift, float* __restrict__ out) {
  size_t i = ((size_t)blockIdx.x * 256 + threadIdx.x) * 4;
  int c = (int)((i >> 13) & 255);
  float sc = scale[c], sh = shift[c];
  u16x4 v = *(const u16x4*)(y + i);
  f32x4 o;
#pragma unroll
  for (int k = 0; k < 4; ++k) o[k] = fmaxf(bf2f(v[k]) * sc + sh, 0.f);
  *(f32x4*)(out + i) = o;
}

// ---------------- launch ----------------

extern "C" void kernel_launch(void* const* d_in, const int* in_sizes, int n_in,
                              void* d_out, int out_size, void* d_ws, size_t ws_size,
                              hipStream_t stream) {
  const float* unknown = (const float*)d_in[0];
  const float* known   = (const float*)d_in[1];
  const float* uf      = (const float*)d_in[2];
  const float* kf      = (const float*)d_in[3];
  const float* W1      = (const float*)d_in[4];
  const float* g1      = (const float*)d_in[5];
  const float* b1      = (const float*)d_in[6];
  const float* W2      = (const float*)d_in[7];
  const float* g2      = (const float*)d_in[8];
  const float* b2      = (const float*)d_in[9];
  float* out = (float*)d_out;

  char* ws = (char*)d_ws;
  unsigned short* xt  = (unsigned short*)(ws);                    // (B,N,768) bf16   100,663,296 B
  unsigned short* y1  = (unsigned short*)(ws + 100663296);        // (B,N,256) bf16    33,554,432 B
  unsigned short* y2  = (unsigned short*)(ws + 134217728);        // (B,256,N) bf16    33,554,432 B
  float*          kft = (float*)(ws + 167772160);                 // (B,M,512) f32     16,777,216 B
  // psum/psq alias kft's region: kft is dead after k_interp; both gemms reuse sequentially
  float*          psum = (float*)(ws + 167772160);                // 256*1024 f32       1,048,576 B
  float*          psq  = (float*)(ws + 168820736);                // 256*1024 f32       1,048,576 B
  unsigned short* w1b = (unsigned short*)(ws + 184549376);        //                      393,216 B
  unsigned short* w2b = (unsigned short*)(ws + 184942592);        //                      131,072 B
  int*            idx = (int*)(ws + 185073664);                   //                      786,432 B
  float*          wgt = (float*)(ws + 185860096);                 //                      786,432 B
  float*          st  = (float*)(ws + 186646528);                 // sc/sh block            4,096 B
  float *sc1 = st, *sh1 = st + 256, *sc2 = st + 512, *sh2 = st + 768;

  k_cast<<<768, 256, 0, stream>>>(W1, w1b, CMID_ * CIN_);
  k_cast<<<256, 256, 0, stream>>>(W2, w2b, COUT_ * CMID_);
  k_tr_kf<<<dim3(16, 32, B_), dim3(32, 8), 0, stream>>>(kf, kft);
  k_tr_uf<<<dim3(8, 256, B_), dim3(32, 8), 0, stream>>>(uf, xt);
  k_three_nn<<<B_ * 256, 256, 0, stream>>>(unknown, known, idx, wgt);
  k_interp<<<B_ * N_ / 8, 256, 0, stream>>>(kft, idx, wgt, xt);
  gemm_bt<CIN_, 0, false><<<dim3(64, B_), 256, 0, stream>>>(w1b, xt, y1, psum, psq, nullptr, nullptr);
  k_finalize<<<256, 256, 0, stream>>>(psum, psq, g1, b1, sc1, sh1);
  gemm_bt<CMID_, 1, true><<<dim3(64, B_), 256, 0, stream>>>(w2b, y1, y2, psum, psq, sc1, sh1);
  k_finalize<<<256, 256, 0, stream>>>(psum, psq, g2, b2, sc2, sh2);
  k_bnrelu_out<<<16384, 256, 0, stream>>>(y2, sc2, sh2, out);
}